// Round 5
// baseline (354.783 us; speedup 1.0000x reference)
//
#include <hip/hip_runtime.h>
#include <stdint.h>

// Soft Decision Tree forward, MI355X (gfx950)
//   xsplit: X -> Xs = [hi|lo] bf16 [32768][1600]
//   wsplit: W_inner -> Ws = [hi|hi|lo|0] bf16 [1024][2432], bias[1024]
//   gemm8 : P = sigmoid(bias + Xs' @ Ws^T); 256x256 tile, BK=32.
//           A: 4-buffer LDS via global_load_lds (64KB -> 2 blocks/CU).
//           B: global->VGPR direct (L2-resident), prefetch 1 tile. 1 barrier/32 MFMA.
//   tree  : path-prob sweep -> y_pred + leaf sums (69KB LDS -> 2 blocks/CU)
//   penalty: tree reduction of leaf sums

#define BROWS 32768
#define KDIM  784
#define NNODE 1023
#define NP    1024
#define NLEAF 1024
#define OUTD  10
#define NDEPTH 10
#define LAMDA 1e-3f

#define GKS   1600          // Xs row stride (hi 800 | lo 800)
#define GKW   2432          // Ws row stride (hi 800 | hi 800 | lo 800 | 32 zeros)
#define NT    76            // K' tiles of 32

typedef __attribute__((ext_vector_type(8))) short short8;
typedef __attribute__((ext_vector_type(4))) float f32x4;

__device__ __forceinline__ unsigned short f2bf(float f) {
    unsigned int u = __float_as_uint(f);
    u = u + 0x7FFFu + ((u >> 16) & 1u);   // RNE
    return (unsigned short)(u >> 16);
}
__device__ __forceinline__ float bf2f(unsigned short h) {
    return __uint_as_float(((unsigned int)h) << 16);
}

// ============================ Pass X: X split =============================
__global__ __launch_bounds__(256)
void sdt_xsplit(const float* __restrict__ X, unsigned short* __restrict__ Xs)
{
    const int g   = blockIdx.x * 256 + threadIdx.x;   // [0, 32768*100)
    const int row = g / 100, grp = g % 100;
    unsigned int hi[4], lo[4];
    if (grp < 98) {
        const float4* src = reinterpret_cast<const float4*>(&X[(size_t)row * KDIM + grp * 8]);
        const float4 v0 = src[0], v1 = src[1];
        const float v[8] = {v0.x, v0.y, v0.z, v0.w, v1.x, v1.y, v1.z, v1.w};
#pragma unroll
        for (int i = 0; i < 4; ++i) {
            const unsigned short h0 = f2bf(v[2*i]), h1 = f2bf(v[2*i+1]);
            const unsigned short l0 = f2bf(v[2*i] - bf2f(h0));
            const unsigned short l1 = f2bf(v[2*i+1] - bf2f(h1));
            hi[i] = (unsigned int)h0 | ((unsigned int)h1 << 16);
            lo[i] = (unsigned int)l0 | ((unsigned int)l1 << 16);
        }
    } else {
#pragma unroll
        for (int i = 0; i < 4; ++i) { hi[i] = 0u; lo[i] = 0u; }
    }
    *reinterpret_cast<uint4*>(&Xs[(size_t)row * GKS + grp * 8])       = make_uint4(hi[0], hi[1], hi[2], hi[3]);
    *reinterpret_cast<uint4*>(&Xs[(size_t)row * GKS + 800 + grp * 8]) = make_uint4(lo[0], lo[1], lo[2], lo[3]);
}

// ============================ Pass W: W split =============================
__global__ __launch_bounds__(256)
void sdt_wsplit(const float* __restrict__ Wi, unsigned short* __restrict__ Ws,
                float* __restrict__ bias)
{
    const int row = blockIdx.x;          // 0..1023
    const int tid = threadIdx.x;
    for (int c = tid; c < GKW; c += 256) {
        unsigned short v = 0;
        if (row < NNODE) {
            if (c < 1600) {                       // two hi sections
                const int k = (c < 800) ? c : c - 800;
                if (k < KDIM) v = f2bf(Wi[(size_t)row * (KDIM + 1) + 1 + k]);
            } else if (c < 2400) {                // lo section
                const int k = c - 1600;
                if (k < KDIM) {
                    const float x = Wi[(size_t)row * (KDIM + 1) + 1 + k];
                    v = f2bf(x - bf2f(f2bf(x)));
                }
            }
        }
        Ws[(size_t)row * GKW + c] = v;
    }
    if (tid == 0) bias[row] = (row < NNODE) ? Wi[(size_t)row * (KDIM + 1)] : 0.f;
}

// ===================== Pass A: 256x256, BK=32, A-in-LDS(4buf) + B-direct =====================
#define BAR() { __builtin_amdgcn_sched_barrier(0); __builtin_amdgcn_s_barrier(); __builtin_amdgcn_sched_barrier(0); }

// stage A tile kt into buffer (kt&3): 2 x 16B global_load_lds per thread
#define STAGE_A(ktn)                                                                  \
    {                                                                                 \
        const int kt_ = (ktn);                                                        \
        const int kA_ = (kt_ < 50) ? kt_ * 32 : kt_ * 32 - 1600;                      \
        unsigned short* ab_ = lds + (kt_ & 3) * 8192;                                 \
        _Pragma("unroll")                                                             \
        for (int j = 0; j < 2; ++j)                                                   \
            __builtin_amdgcn_global_load_lds(                                         \
                (const __attribute__((address_space(1))) void*)(pA[j] + kA_),         \
                (__attribute__((address_space(3))) void*)(ab_ + (j * 512 + wave * 64) * 8), \
                16, 0, 0);                                                            \
    }

// A fragment reads: row stride 32 shorts (64B); slot swizzle q4 ^ ((row>>1)&3)
#define LDA4(dst, mb, ab_)                                                            \
    _Pragma("unroll")                                                                 \
    for (int mi = 0; mi < 4; ++mi) {                                                  \
        const int row_ = wr * 128 + ((mb) + mi) * 16 + fr;                            \
        dst[mi] = *reinterpret_cast<const short8*>(                                   \
            (ab_) + row_ * 32 + ((q4 ^ ((row_ >> 1) & 3)) * 8));                      \
    }

// B fragment loads: global (L2-resident Ws), exact MFMA layout per lane
#define LDBG(dst, ktn)                                                                \
    _Pragma("unroll")                                                                 \
    for (int n = 0; n < 4; ++n)                                                       \
        dst[n] = *reinterpret_cast<const short8*>(pB[n] + (ktn) * 32);

#define MFMA16(mb, av, bv)                                                            \
    _Pragma("unroll")                                                                 \
    for (int mi = 0; mi < 4; ++mi)                                                    \
        _Pragma("unroll")                                                             \
        for (int n = 0; n < 4; ++n)                                                   \
            acc[(mb) + mi][n] = __builtin_amdgcn_mfma_f32_16x16x32_bf16(              \
                av[mi], bv[n], acc[(mb) + mi][n], 0, 0, 0);

__global__ __launch_bounds__(512, 2)
void sdt_gemm8(const unsigned short* __restrict__ Xs, const unsigned short* __restrict__ Ws,
               const float* __restrict__ bias, unsigned short* __restrict__ P)
{
    __shared__ __align__(16) unsigned short lds[32768];   // 64 KB = 4 x 16KB A buffers

    const int tid  = threadIdx.x;
    const int wave = tid >> 6, lane = tid & 63;
    const int wr = wave >> 2, wc = wave & 3;              // 2x4 wave grid -> 128x64 per wave
    // XCD-aware swizzle: 512 blocks, 64 contiguous per XCD
    const int b  = blockIdx.x;
    const int wg = (b & 7) * 64 + (b >> 3);
    const int col0 = (wg & 3) * 256;
    const int row0 = (wg >> 2) * 256;

    const int fr = lane & 15;
    const int q4 = lane >> 4;

    f32x4 acc[8][4];
#pragma unroll
    for (int i = 0; i < 8; ++i)
#pragma unroll
        for (int j = 0; j < 4; ++j) acc[i][j] = (f32x4)0.f;

    // A staging sources: chunk c = j*512 + tid -> (r = c>>2, slot = c&3,
    // logical kc = slot ^ ((r>>1)&3)); global addr pre-inverse-swizzled.
    const unsigned short* pA[2];
#pragma unroll
    for (int j = 0; j < 2; ++j) {
        const int c = j * 512 + tid;
        const int r = c >> 2;
        const int kc = (c & 3) ^ ((r >> 1) & 3);
        pA[j] = Xs + (size_t)(row0 + r) * GKS + kc * 8;
    }
    // B fragment bases (per lane): row = col0 + wc*64 + n*16 + fr, k-slot q4
    const unsigned short* pB[4];
#pragma unroll
    for (int n = 0; n < 4; ++n)
        pB[n] = Ws + (size_t)(col0 + wc * 64 + n * 16 + fr) * GKW + q4 * 8;

    short8 bcur[4], bnxt[4];

    // prologue: stage tiles 0,1; load B(0); drain the two A-stages
    STAGE_A(0);
    STAGE_A(1);
    LDBG(bcur, 0);
    asm volatile("s_waitcnt vmcnt(4)" ::: "memory");   // S_A(0), S_A(1) landed

#pragma unroll 1
    for (int kt = 0; kt < NT - 2; ++kt) {
        const unsigned short* ab = lds + (kt & 3) * 8192;
        STAGE_A(kt + 2);          // 2 vm ops
        LDBG(bnxt, kt + 1);       // 4 vm ops
        // steady state: 16 vm ops issued after S_A(kt) -> vmcnt(16) drains S_A(kt)
        asm volatile("s_waitcnt vmcnt(16)" ::: "memory");
        BAR();                    // all waves' S_A(kt) landed; buffer reuse fence
        short8 a0[4], a1[4];
        LDA4(a0, 0, ab);
        LDA4(a1, 4, ab);
        __builtin_amdgcn_s_setprio(1);
        MFMA16(0, a0, bcur);
        MFMA16(4, a1, bcur);
        __builtin_amdgcn_s_setprio(0);
#pragma unroll
        for (int n = 0; n < 4; ++n) bcur[n] = bnxt[n];
    }

    // tail: tiles NT-2, NT-1 (no A prefetch; conservative drains)
#pragma unroll 1
    for (int kt = NT - 2; kt < NT; ++kt) {
        const unsigned short* ab = lds + (kt & 3) * 8192;
        if (kt + 1 < NT) LDBG(bnxt, kt + 1);
        asm volatile("s_waitcnt vmcnt(0)" ::: "memory");
        BAR();
        short8 a0[4], a1[4];
        LDA4(a0, 0, ab);
        LDA4(a1, 4, ab);
        __builtin_amdgcn_s_setprio(1);
        MFMA16(0, a0, bcur);
        MFMA16(4, a1, bcur);
        __builtin_amdgcn_s_setprio(0);
#pragma unroll
        for (int n = 0; n < 4; ++n) bcur[n] = bnxt[n];
    }

    // ---- epilogue: bias + sigmoid, per-wave LDS transpose in 2 halves ----
    __syncthreads();                          // all K-loop LDS reads done
    unsigned short* tr = lds + wave * 4096;   // 8 KB per wave (64 rows x 64 cols bf16)
    float bv[4];
#pragma unroll
    for (int n = 0; n < 4; ++n) bv[n] = bias[col0 + wc * 64 + n * 16 + fr];

#pragma unroll
    for (int half = 0; half < 2; ++half) {
#pragma unroll
        for (int m = 0; m < 4; ++m)
#pragma unroll
            for (int reg = 0; reg < 4; ++reg) {
                const int rl = m * 16 + q4 * 4 + reg;      // 0..63 within half
#pragma unroll
                for (int n = 0; n < 4; ++n) {
                    const float z = acc[half * 4 + m][n][reg] + bv[n];
                    const float p = 1.f / (1.f + __expf(-z));
                    tr[rl * 64 + n * 16 + fr] = f2bf(p);
                }
            }
        // wave-private readback (compiler inserts lgkm waits; no barrier needed)
#pragma unroll
        for (int it = 0; it < 8; ++it) {
            const int r  = it * 8 + (lane >> 3);
            const int c8 = (lane & 7) * 8;
            const uint4 v = *reinterpret_cast<const uint4*>(tr + r * 64 + c8);
            *reinterpret_cast<uint4*>(
                &P[(size_t)(row0 + wr * 128 + half * 64 + r) * NP + col0 + wc * 64 + c8]) = v;
        }
    }
}

// ===================== Pass B: tree sweep + leaf GEMV + leaf sums =====================
__global__ __launch_bounds__(256)
void sdt_tree(const unsigned short* __restrict__ P, const float* __restrict__ Wl,
              float* __restrict__ Y, float* __restrict__ leafsum)
{
    __shared__ float wl[OUTD * NLEAF];                       // 40 KB
    __shared__ __align__(16) unsigned short plb[4][2][1024]; // 16 KB bf16 p-rows (dbuf/wave)
    __shared__ float red[4][832];                            // 13 KB y-reduction (stride 13)
    // leaf-sum scratch aliases plb (used after all row compute; exact 16 KB)
    float* fbuf = reinterpret_cast<float*>(&plb[0][0][0]);
    const int tid = threadIdx.x;
    const int wave = tid >> 6, lane = tid & 63;

    for (int idx = tid; idx < (OUTD * NLEAF) / 4; idx += 256)
        reinterpret_cast<float4*>(wl)[idx] = reinterpret_cast<const float4*>(Wl)[idx];
    __syncthreads();

    float lsum[16];
#pragma unroll
    for (int i = 0; i < 16; ++i) lsum[i] = 0.f;

    float* rd = red[wave];
    const int rowbase = blockIdx.x * 32 + wave * 8;
    const int o_r   = lane % 10;            // reduction role (lanes < 40)
    const int seg16 = (lane / 10) * 16;
    const int rot   = (lane >> 1) & 3;      // wl float4 rotation (bank spread)

    // prefetch row 0
    uint4 v0 = reinterpret_cast<const uint4*>(P + (size_t)rowbase * NP)[lane];
    uint4 v1 = reinterpret_cast<const uint4*>(P + (size_t)rowbase * NP)[lane + 64];

    for (int r = 0; r < 8; ++r) {
        const int row = rowbase + r;
        unsigned short* plw = plb[wave][r & 1];
        *reinterpret_cast<uint4*>(&plw[lane * 8])        = v0;   // 2x ds_write_b128
        *reinterpret_cast<uint4*>(&plw[(lane + 64) * 8]) = v1;
        if (r < 7) {   // prefetch next row under this row's compute (T14)
            v0 = reinterpret_cast<const uint4*>(P + (size_t)(row + 1) * NP)[lane];
            v1 = reinterpret_cast<const uint4*>(P + (size_t)(row + 1) * NP)[lane + 64];
        }

        // tree walk: root -> depth-6 node (63+lane)
        float mu = 1.f; int node = 0;
#pragma unroll
        for (int d = 0; d < 6; ++d) {
            const int bit = (lane >> (5 - d)) & 1;
            const float pv = bf2f(plw[node]);
            mu *= bit ? (1.f - pv) : pv;
            node = 2 * node + 1 + bit;
        }
        float m1[2], m2[4], m3[8], m4[16];
        {
            const float pv = bf2f(plw[63 + lane]);
            m1[0] = mu * pv; m1[1] = mu * (1.f - pv);
        }
#pragma unroll
        for (int i = 0; i < 2; ++i) {
            const float pv = bf2f(plw[127 + 2 * lane + i]);
            m2[2 * i] = m1[i] * pv; m2[2 * i + 1] = m1[i] * (1.f - pv);
        }
#pragma unroll
        for (int i = 0; i < 4; ++i) {
            const float pv = bf2f(plw[255 + 4 * lane + i]);
            m3[2 * i] = m2[i] * pv; m3[2 * i + 1] = m2[i] * (1.f - pv);
        }
#pragma unroll
        for (int i = 0; i < 8; ++i) {
            const float pv = bf2f(plw[511 + 8 * lane + i]);
            m4[2 * i] = m3[i] * pv; m4[2 * i + 1] = m3[i] * (1.f - pv);
        }
#pragma unroll
        for (int i = 0; i < 16; ++i) lsum[i] += m4[i];

        // y partials: lane owns leaves lane*16..+15; rotated float4 reads
#pragma unroll
        for (int o = 0; o < OUTD; ++o) {
            float s = 0.f;
#pragma unroll
            for (int i4p = 0; i4p < 4; ++i4p) {
                const int i4 = (i4p + rot) & 3;
                const float4 w4 = *reinterpret_cast<const float4*>(&wl[o * NLEAF + lane * 16 + i4 * 4]);
                s = fmaf(m4[4 * i4 + 0], w4.x, s);
                s = fmaf(m4[4 * i4 + 1], w4.y, s);
                s = fmaf(m4[4 * i4 + 2], w4.z, s);
                s = fmaf(m4[4 * i4 + 3], w4.w, s);
            }
            rd[lane * 13 + o] = s;
        }
        // reduce 64 partials per output via LDS transpose + 2 shuffles
        float s = 0.f;
        if (lane < 40) {
#pragma unroll
            for (int m = 0; m < 16; ++m) s += rd[(seg16 + m) * 13 + o_r];
        }
        s += __shfl_down(s, 20, 64);
        s += __shfl_down(s, 10, 64);
        if (lane < 10) Y[(size_t)row * OUTD + lane] = s;
    }

    __syncthreads();   // p-row buffers dead; reuse as leaf-sum scratch
#pragma unroll
    for (int i = 0; i < 16; ++i) {
        const int ii = (i + lane) & 15;
        fbuf[wave * NP + lane * 16 + ii] = lsum[ii];
    }
    __syncthreads();
    for (int idx = tid; idx < NLEAF; idx += 256) {
        const float s = fbuf[0 * NP + idx] + fbuf[1 * NP + idx] +
                        fbuf[2 * NP + idx] + fbuf[3 * NP + idx];
        atomicAdd(&leafsum[idx], s);
    }
}

// ============================ Pass C: penalty ============================
__global__ __launch_bounds__(1024)
void sdt_penalty(const float* __restrict__ leafsum, float* __restrict__ pen_out)
{
    __shared__ float t[NLEAF];
    __shared__ float red1[1024];
    const int tid = threadIdx.x;
    t[tid] = leafsum[tid];
    __syncthreads();
    float pen = 0.f;
    for (int d = NDEPTH; d >= 1; --d) {
        const int n = 1 << d;
        if (tid < n) {
            const float num = t[tid];
            const float par = t[tid & ~1] + t[tid | 1];
            const float a = num / par;
            const float coeff = LAMDA * exp2f((float)(1 - d));
            pen -= 0.5f * coeff * (logf(a) + logf(1.f - a));
        }
        float s = 0.f;
        if (tid < (n >> 1)) s = t[2 * tid] + t[2 * tid + 1];
        __syncthreads();
        if (tid < (n >> 1)) t[tid] = s;
        __syncthreads();
    }
    red1[tid] = pen;
    __syncthreads();
    for (int off = 512; off >= 1; off >>= 1) {
        if (tid < off) red1[tid] += red1[tid + off];
        __syncthreads();
    }
    if (tid == 0) pen_out[0] = red1[0];
}

// ================================ launch ================================
extern "C" void kernel_launch(void* const* d_in, const int* in_sizes, int n_in,
                              void* d_out, int out_size, void* d_ws, size_t ws_size,
                              hipStream_t stream)
{
    const float* X  = (const float*)d_in[0];
    const float* Wi = (const float*)d_in[1];
    const float* Wl = (const float*)d_in[2];
    float* Y   = (float*)d_out;
    float* pen = Y + (size_t)BROWS * OUTD;

    char* ws = (char*)d_ws;
    const size_t P_BYTES  = (size_t)BROWS * NP * 2;            // 67,108,864
    const size_t XS_BYTES = (size_t)BROWS * GKS * 2;           // 104,857,600
    const size_t WS_BYTES = (size_t)NP * GKW * 2;              // 4,980,736

    unsigned short* P   = (unsigned short*)ws;
    unsigned short* Xs  = (unsigned short*)(ws + P_BYTES);
    unsigned short* Wsp = (unsigned short*)(ws + P_BYTES + XS_BYTES);
    float* bias    = (float*)(ws + P_BYTES + XS_BYTES + WS_BYTES);
    float* leafsum = (float*)(ws + P_BYTES + XS_BYTES + WS_BYTES + 4096);

    hipMemsetAsync(leafsum, 0, NLEAF * sizeof(float), stream);
    sdt_xsplit<<<BROWS * 100 / 256, 256, 0, stream>>>(X, Xs);
    sdt_wsplit<<<1024, 256, 0, stream>>>(Wi, Wsp, bias);
    sdt_gemm8<<<512, 512, 0, stream>>>(Xs, Wsp, bias, P);
    sdt_tree<<<BROWS / 32, 256, 0, stream>>>(P, Wl, Y, leafsum);
    sdt_penalty<<<1, 1024, 0, stream>>>(leafsum, pen);
}

// Round 6
// 229.762 us; speedup vs baseline: 1.5441x; 1.5441x over previous
//
#include <hip/hip_runtime.h>
#include <stdint.h>

// Soft Decision Tree forward, MI355X (gfx950)
//   xsplit: X -> Xs = [hi|lo] bf16 [32768][1600]
//   wsplit: W_inner -> Ws = [hi|hi] bf16 [1024][1600], bias[1024]
//   gemm8 : P = sigmoid(bias + Xs @ Ws^T), K'=1600 (2-term split: AhBh + AlBh);
//           256x256 tile, BK=32, 4-buffer LDS, distance-2 prefetch, counted vmcnt
//   tree  : path-prob sweep -> y_pred + leaf sums (round-3 proven version)
//   penalty: tree reduction of leaf sums

#define BROWS 32768
#define KDIM  784
#define NNODE 1023
#define NP    1024
#define NLEAF 1024
#define OUTD  10
#define NDEPTH 10
#define LAMDA 1e-3f

#define GKS   1600          // Xs row stride (hi 800 | lo 800)
#define GKW   1600          // Ws row stride (hi 800 | hi 800)
#define NT    50            // K' tiles of 32

typedef __attribute__((ext_vector_type(8))) short short8;
typedef __attribute__((ext_vector_type(4))) float f32x4;

__device__ __forceinline__ unsigned short f2bf(float f) {
    unsigned int u = __float_as_uint(f);
    u = u + 0x7FFFu + ((u >> 16) & 1u);   // RNE
    return (unsigned short)(u >> 16);
}
__device__ __forceinline__ float bf2f(unsigned short h) {
    return __uint_as_float(((unsigned int)h) << 16);
}

// ============================ Pass X: X split =============================
__global__ __launch_bounds__(256)
void sdt_xsplit(const float* __restrict__ X, unsigned short* __restrict__ Xs)
{
    const int g   = blockIdx.x * 256 + threadIdx.x;   // [0, 32768*100)
    const int row = g / 100, grp = g % 100;
    unsigned int hi[4], lo[4];
    if (grp < 98) {
        const float4* src = reinterpret_cast<const float4*>(&X[(size_t)row * KDIM + grp * 8]);
        const float4 v0 = src[0], v1 = src[1];
        const float v[8] = {v0.x, v0.y, v0.z, v0.w, v1.x, v1.y, v1.z, v1.w};
#pragma unroll
        for (int i = 0; i < 4; ++i) {
            const unsigned short h0 = f2bf(v[2*i]), h1 = f2bf(v[2*i+1]);
            const unsigned short l0 = f2bf(v[2*i] - bf2f(h0));
            const unsigned short l1 = f2bf(v[2*i+1] - bf2f(h1));
            hi[i] = (unsigned int)h0 | ((unsigned int)h1 << 16);
            lo[i] = (unsigned int)l0 | ((unsigned int)l1 << 16);
        }
    } else {
#pragma unroll
        for (int i = 0; i < 4; ++i) { hi[i] = 0u; lo[i] = 0u; }
    }
    *reinterpret_cast<uint4*>(&Xs[(size_t)row * GKS + grp * 8])       = make_uint4(hi[0], hi[1], hi[2], hi[3]);
    *reinterpret_cast<uint4*>(&Xs[(size_t)row * GKS + 800 + grp * 8]) = make_uint4(lo[0], lo[1], lo[2], lo[3]);
}

// ============================ Pass W: W split =============================
__global__ __launch_bounds__(256)
void sdt_wsplit(const float* __restrict__ Wi, unsigned short* __restrict__ Ws,
                float* __restrict__ bias)
{
    const int row = blockIdx.x;          // 0..1023
    const int tid = threadIdx.x;
    for (int c = tid; c < GKW; c += 256) {
        unsigned short v = 0;
        if (row < NNODE) {
            const int k = (c < 800) ? c : c - 800;   // [hi | hi]
            if (k < KDIM) v = f2bf(Wi[(size_t)row * (KDIM + 1) + 1 + k]);
        }
        Ws[(size_t)row * GKW + c] = v;
    }
    if (tid == 0) bias[row] = (row < NNODE) ? Wi[(size_t)row * (KDIM + 1)] : 0.f;
}

// ===================== Pass A: 256x256, BK=32, 4-buffer counted-vmcnt MFMA =====================
#define BAR() { __builtin_amdgcn_sched_barrier(0); __builtin_amdgcn_s_barrier(); __builtin_amdgcn_sched_barrier(0); }

// stage tile kt into buffer (kt&3): 2 A-loads + 2 B-loads per thread (16B each)
#define STAGE(ktn)                                                                    \
    {                                                                                 \
        const int kt_ = (ktn);                                                        \
        const int kk_ = kt_ * 32;                                                     \
        unsigned short* ab_ = lds + (kt_ & 3) * 16384;                                \
        unsigned short* bb_ = ab_ + 8192;                                             \
        _Pragma("unroll")                                                             \
        for (int j = 0; j < 2; ++j)                                                   \
            __builtin_amdgcn_global_load_lds(                                         \
                (const __attribute__((address_space(1))) void*)(pA[j] + kk_),         \
                (__attribute__((address_space(3))) void*)(ab_ + (j * 512 + wave * 64) * 8), \
                16, 0, 0);                                                            \
        _Pragma("unroll")                                                             \
        for (int j = 0; j < 2; ++j)                                                   \
            __builtin_amdgcn_global_load_lds(                                         \
                (const __attribute__((address_space(1))) void*)(pB[j] + kk_),         \
                (__attribute__((address_space(3))) void*)(bb_ + (j * 512 + wave * 64) * 8), \
                16, 0, 0);                                                            \
    }

// fragment reads: row stride 32 shorts (64B); slot swizzle q4 ^ ((row>>1)&3)
#define LDA4(dst, mb, ab_)                                                            \
    _Pragma("unroll")                                                                 \
    for (int mi = 0; mi < 4; ++mi) {                                                  \
        const int row_ = wr * 128 + ((mb) + mi) * 16 + fr;                            \
        dst[mi] = *reinterpret_cast<const short8*>(                                   \
            (ab_) + row_ * 32 + ((q4 ^ ((row_ >> 1) & 3)) * 8));                      \
    }

#define LDB4(dst, bb_)                                                                \
    _Pragma("unroll")                                                                 \
    for (int n = 0; n < 4; ++n) {                                                     \
        const int row_ = wc * 64 + n * 16 + fr;                                       \
        dst[n] = *reinterpret_cast<const short8*>(                                    \
            (bb_) + row_ * 32 + ((q4 ^ ((row_ >> 1) & 3)) * 8));                      \
    }

#define MFMA16(mb, av, bv)                                                            \
    _Pragma("unroll")                                                                 \
    for (int mi = 0; mi < 4; ++mi)                                                    \
        _Pragma("unroll")                                                             \
        for (int n = 0; n < 4; ++n)                                                   \
            acc[(mb) + mi][n] = __builtin_amdgcn_mfma_f32_16x16x32_bf16(              \
                av[mi], bv[n], acc[(mb) + mi][n], 0, 0, 0);

__global__ __launch_bounds__(512, 2)
void sdt_gemm8(const unsigned short* __restrict__ Xs, const unsigned short* __restrict__ Ws,
               const float* __restrict__ bias, unsigned short* __restrict__ P)
{
    __shared__ __align__(16) unsigned short lds[65536];   // 128 KB = 4 buf x (A 16KB + B 16KB)

    const int tid  = threadIdx.x;
    const int wave = tid >> 6, lane = tid & 63;
    const int wr = wave >> 2, wc = wave & 3;              // 2x4 wave grid -> 128x64 per wave
    // XCD-aware swizzle: 512 blocks, 64 contiguous per XCD
    const int b  = blockIdx.x;
    const int wg = (b & 7) * 64 + (b >> 3);
    const int col0 = (wg & 3) * 256;
    const int row0 = (wg >> 2) * 256;

    const int fr = lane & 15;
    const int q4 = lane >> 4;

    f32x4 acc[8][4];
#pragma unroll
    for (int i = 0; i < 8; ++i)
#pragma unroll
        for (int j = 0; j < 4; ++j) acc[i][j] = (f32x4)0.f;

    // staging sources: chunk c = j*512 + tid -> (r = c>>2, slot = c&3,
    // logical kc = slot ^ ((r>>1)&3)); global addr pre-inverse-swizzled.
    const unsigned short* pA[2];
    const unsigned short* pB[2];
#pragma unroll
    for (int j = 0; j < 2; ++j) {
        const int c = j * 512 + tid;
        const int r = c >> 2;
        const int kc = (c & 3) ^ ((r >> 1) & 3);
        pA[j] = Xs + (size_t)(row0 + r) * GKS + kc * 8;
        pB[j] = Ws + (size_t)(col0 + r) * GKW + kc * 8;
    }

    STAGE(0);
    STAGE(1);
    asm volatile("s_waitcnt vmcnt(4)" ::: "memory");   // tile 0 staged; tile 1 in flight
    BAR();

#pragma unroll 1
    for (int kt = 0; kt < NT; ++kt) {
        const unsigned short* ab = lds + (kt & 3) * 16384;
        const unsigned short* bb = ab + 8192;
        short8 a[4], bfr[4];

        // ---- phase 0: m0-3 ----
        LDA4(a, 0, ab);
        LDB4(bfr, bb);
        if (kt + 2 < NT) STAGE(kt + 2);
        BAR();
        __builtin_amdgcn_s_setprio(1);
        MFMA16(0, a, bfr);
        __builtin_amdgcn_s_setprio(0);
        BAR();
        // ---- phase 1: m4-7 ----
        LDA4(a, 4, ab);
        // counted wait: tile kt+1's 4 loads were issued at tile kt-1 (4 phases ago)
        asm volatile("s_waitcnt vmcnt(4)" ::: "memory");
        BAR();
        __builtin_amdgcn_s_setprio(1);
        MFMA16(4, a, bfr);
        __builtin_amdgcn_s_setprio(0);
        BAR();
    }

    // ---- epilogue: bias + sigmoid, per-wave LDS transpose, coalesced stores ----
    __syncthreads();
    unsigned short* tr = lds + wave * 8192;   // 16 KB per wave (128 rows x 64 cols bf16)
    float bv[4];
#pragma unroll
    for (int n = 0; n < 4; ++n) bv[n] = bias[col0 + wc * 64 + n * 16 + fr];

#pragma unroll
    for (int m = 0; m < 8; ++m)
#pragma unroll
        for (int reg = 0; reg < 4; ++reg) {
            const int rl = m * 16 + q4 * 4 + reg;
#pragma unroll
            for (int n = 0; n < 4; ++n) {
                const float z = acc[m][n][reg] + bv[n];
                const float p = 1.f / (1.f + __expf(-z));
                tr[rl * 64 + n * 16 + fr] = f2bf(p);
            }
        }
    // wave-private readback (no barrier needed)
#pragma unroll
    for (int it = 0; it < 16; ++it) {
        const int r  = it * 8 + (lane >> 3);
        const int c8 = (lane & 7) * 8;
        const uint4 v = *reinterpret_cast<const uint4*>(tr + r * 64 + c8);
        *reinterpret_cast<uint4*>(
            &P[(size_t)(row0 + wr * 128 + r) * NP + col0 + wc * 64 + c8]) = v;
    }
}

// ===================== Pass B: tree sweep + leaf GEMV + leaf sums =====================
// round-3 proven version (float LDS staging, 69 KB -> 2 blocks/CU)
__global__ __launch_bounds__(256)
void sdt_tree(const unsigned short* __restrict__ P, const float* __restrict__ Wl,
              float* __restrict__ Y, float* __restrict__ leafsum)
{
    __shared__ float wl[OUTD * NLEAF];   // 40 KB
    __shared__ float buf[4][NP];         // 16 KB (p row / leaf-sum scratch)
    __shared__ float red[4][832];        // 13 KB (y reduction, stride 13)
    const int tid = threadIdx.x;
    const int wave = tid >> 6, lane = tid & 63;

    for (int idx = tid; idx < (OUTD * NLEAF) / 4; idx += 256)
        reinterpret_cast<float4*>(wl)[idx] = reinterpret_cast<const float4*>(Wl)[idx];
    __syncthreads();

    float lsum[16];
#pragma unroll
    for (int i = 0; i < 16; ++i) lsum[i] = 0.f;

    float* pl = buf[wave];
    float* rd = red[wave];
    const int rowbase = blockIdx.x * 32 + wave * 8;
    const int o_r   = lane % 10;            // reduction role (lanes < 40)
    const int seg16 = (lane / 10) * 16;

    for (int r = 0; r < 8; ++r) {
        const int row = rowbase + r;
        const uint4* prow = reinterpret_cast<const uint4*>(P + (size_t)row * NP);
#pragma unroll
        for (int c = 0; c < 2; ++c) {
            const uint4 v = prow[lane + 64 * c];
            const int base = (lane + 64 * c) * 8;
            pl[base + 0] = bf2f((unsigned short)(v.x & 0xffffu));
            pl[base + 1] = bf2f((unsigned short)(v.x >> 16));
            pl[base + 2] = bf2f((unsigned short)(v.y & 0xffffu));
            pl[base + 3] = bf2f((unsigned short)(v.y >> 16));
            pl[base + 4] = bf2f((unsigned short)(v.z & 0xffffu));
            pl[base + 5] = bf2f((unsigned short)(v.z >> 16));
            pl[base + 6] = bf2f((unsigned short)(v.w & 0xffffu));
            pl[base + 7] = bf2f((unsigned short)(v.w >> 16));
        }

        // tree walk: root -> depth-6 node (63+lane)
        float mu = 1.f; int node = 0;
#pragma unroll
        for (int d = 0; d < 6; ++d) {
            const int bit = (lane >> (5 - d)) & 1;
            const float pv = pl[node];
            mu *= bit ? (1.f - pv) : pv;
            node = 2 * node + 1 + bit;
        }
        float m1[2], m2[4], m3[8], m4[16];
        {
            const float pv = pl[63 + lane];
            m1[0] = mu * pv; m1[1] = mu * (1.f - pv);
        }
#pragma unroll
        for (int i = 0; i < 2; ++i) {
            const float pv = pl[127 + 2 * lane + i];
            m2[2 * i] = m1[i] * pv; m2[2 * i + 1] = m1[i] * (1.f - pv);
        }
#pragma unroll
        for (int i = 0; i < 4; ++i) {
            const float pv = pl[255 + 4 * lane + i];
            m3[2 * i] = m2[i] * pv; m3[2 * i + 1] = m2[i] * (1.f - pv);
        }
#pragma unroll
        for (int i = 0; i < 8; ++i) {
            const float pv = pl[511 + 8 * lane + i];
            m4[2 * i] = m3[i] * pv; m4[2 * i + 1] = m3[i] * (1.f - pv);
        }
#pragma unroll
        for (int i = 0; i < 16; ++i) lsum[i] += m4[i];

        // y partials: lane owns leaves lane*16..+15, float4 wl reads
#pragma unroll
        for (int o = 0; o < OUTD; ++o) {
            float s = 0.f;
#pragma unroll
            for (int i4 = 0; i4 < 4; ++i4) {
                const float4 w4 = *reinterpret_cast<const float4*>(&wl[o * NLEAF + lane * 16 + i4 * 4]);
                s = fmaf(m4[4 * i4 + 0], w4.x, s);
                s = fmaf(m4[4 * i4 + 1], w4.y, s);
                s = fmaf(m4[4 * i4 + 2], w4.z, s);
                s = fmaf(m4[4 * i4 + 3], w4.w, s);
            }
            rd[lane * 13 + o] = s;
        }
        // reduce 64 partials per output via LDS transpose + 2 shuffles
        float s = 0.f;
        if (lane < 40) {
#pragma unroll
            for (int m = 0; m < 16; ++m) s += rd[(seg16 + m) * 13 + o_r];
        }
        s += __shfl_down(s, 20, 64);
        s += __shfl_down(s, 10, 64);
        if (lane < 10) Y[(size_t)row * OUTD + lane] = s;
    }

    __syncthreads();
#pragma unroll
    for (int i = 0; i < 16; ++i) {
        const int ii = (i + lane) & 15;
        buf[wave][lane * 16 + ii] = lsum[ii];
    }
    __syncthreads();
    for (int idx = tid; idx < NLEAF; idx += 256) {
        const float s = buf[0][idx] + buf[1][idx] + buf[2][idx] + buf[3][idx];
        atomicAdd(&leafsum[idx], s);
    }
}

// ============================ Pass C: penalty ============================
__global__ __launch_bounds__(1024)
void sdt_penalty(const float* __restrict__ leafsum, float* __restrict__ pen_out)
{
    __shared__ float t[NLEAF];
    __shared__ float red1[1024];
    const int tid = threadIdx.x;
    t[tid] = leafsum[tid];
    __syncthreads();
    float pen = 0.f;
    for (int d = NDEPTH; d >= 1; --d) {
        const int n = 1 << d;
        if (tid < n) {
            const float num = t[tid];
            const float par = t[tid & ~1] + t[tid | 1];
            const float a = num / par;
            const float coeff = LAMDA * exp2f((float)(1 - d));
            pen -= 0.5f * coeff * (logf(a) + logf(1.f - a));
        }
        float s = 0.f;
        if (tid < (n >> 1)) s = t[2 * tid] + t[2 * tid + 1];
        __syncthreads();
        if (tid < (n >> 1)) t[tid] = s;
        __syncthreads();
    }
    red1[tid] = pen;
    __syncthreads();
    for (int off = 512; off >= 1; off >>= 1) {
        if (tid < off) red1[tid] += red1[tid + off];
        __syncthreads();
    }
    if (tid == 0) pen_out[0] = red1[0];
}

// ================================ launch ================================
extern "C" void kernel_launch(void* const* d_in, const int* in_sizes, int n_in,
                              void* d_out, int out_size, void* d_ws, size_t ws_size,
                              hipStream_t stream)
{
    const float* X  = (const float*)d_in[0];
    const float* Wi = (const float*)d_in[1];
    const float* Wl = (const float*)d_in[2];
    float* Y   = (float*)d_out;
    float* pen = Y + (size_t)BROWS * OUTD;

    char* ws = (char*)d_ws;
    const size_t P_BYTES  = (size_t)BROWS * NP * 2;            // 67,108,864
    const size_t XS_BYTES = (size_t)BROWS * GKS * 2;           // 104,857,600
    const size_t WS_BYTES = (size_t)NP * GKW * 2;              // 3,276,800

    unsigned short* P   = (unsigned short*)ws;
    unsigned short* Xs  = (unsigned short*)(ws + P_BYTES);
    unsigned short* Wsp = (unsigned short*)(ws + P_BYTES + XS_BYTES);
    float* bias    = (float*)(ws + P_BYTES + XS_BYTES + WS_BYTES);
    float* leafsum = (float*)(ws + P_BYTES + XS_BYTES + WS_BYTES + 4096);

    hipMemsetAsync(leafsum, 0, NLEAF * sizeof(float), stream);
    sdt_xsplit<<<BROWS * 100 / 256, 256, 0, stream>>>(X, Xs);
    sdt_wsplit<<<1024, 256, 0, stream>>>(Wi, Wsp, bias);
    sdt_gemm8<<<512, 512, 0, stream>>>(Xs, Wsp, bias, P);
    sdt_tree<<<BROWS / 32, 256, 0, stream>>>(P, Wl, Y, leafsum);
    sdt_penalty<<<1, 1024, 0, stream>>>(leafsum, pen);
}

// Round 7
// 174.931 us; speedup vs baseline: 2.0281x; 1.3134x over previous
//
#include <hip/hip_runtime.h>
#include <stdint.h>

// Soft Decision Tree forward, MI355X (gfx950)
//   xsplit: X -> Xs = bf16(X) [32768][800]                  (pure cast)
//   wsplit: W_inner -> Ws = bf16 [1024][800], bias[1024]
//   gemm8 : P = sigmoid(bias + Xs @ Ws^T), K=800 pure bf16 MFMA;
//           256x256 tile, BK=32, 4-buffer LDS, distance-2 prefetch,
//           counted vmcnt(4) steady state / vmcnt(0) tail (race-free)
//   tree  : path-prob sweep -> y_pred + leaf sums (round-3 proven version)
//   penalty: tree reduction of leaf sums
// Error budget: z-noise std ~4.5e-3 -> y absmax ~3e-4 (P bf16-storage dominated),
// threshold 7.86e-4. Validated ladder: f32 GEMM 2.441e-4; 3-term 2.441e-4;
// 2-term 2.441e-4 (z-noise invisible on y).

#define BROWS 32768
#define KDIM  784
#define NNODE 1023
#define NP    1024
#define NLEAF 1024
#define OUTD  10
#define NDEPTH 10
#define LAMDA 1e-3f

#define GKS   800           // Xs row stride
#define GKW   800           // Ws row stride
#define NT    25            // K tiles of 32

typedef __attribute__((ext_vector_type(8))) short short8;
typedef __attribute__((ext_vector_type(4))) float f32x4;

__device__ __forceinline__ unsigned short f2bf(float f) {
    unsigned int u = __float_as_uint(f);
    u = u + 0x7FFFu + ((u >> 16) & 1u);   // RNE
    return (unsigned short)(u >> 16);
}
__device__ __forceinline__ float bf2f(unsigned short h) {
    return __uint_as_float(((unsigned int)h) << 16);
}

// ============================ Pass X: cast X -> bf16 =============================
__global__ __launch_bounds__(256)
void sdt_xsplit(const float* __restrict__ X, unsigned short* __restrict__ Xs)
{
    const int g   = blockIdx.x * 256 + threadIdx.x;   // [0, 32768*100)
    const int row = g / 100, grp = g % 100;
    unsigned int hi[4];
    if (grp < 98) {
        const float4* src = reinterpret_cast<const float4*>(&X[(size_t)row * KDIM + grp * 8]);
        const float4 v0 = src[0], v1 = src[1];
        const float v[8] = {v0.x, v0.y, v0.z, v0.w, v1.x, v1.y, v1.z, v1.w};
#pragma unroll
        for (int i = 0; i < 4; ++i)
            hi[i] = (unsigned int)f2bf(v[2*i]) | ((unsigned int)f2bf(v[2*i+1]) << 16);
    } else {
#pragma unroll
        for (int i = 0; i < 4; ++i) hi[i] = 0u;
    }
    *reinterpret_cast<uint4*>(&Xs[(size_t)row * GKS + grp * 8]) = make_uint4(hi[0], hi[1], hi[2], hi[3]);
}

// ============================ Pass W: cast W -> bf16 =============================
__global__ __launch_bounds__(256)
void sdt_wsplit(const float* __restrict__ Wi, unsigned short* __restrict__ Ws,
                float* __restrict__ bias)
{
    const int row = blockIdx.x;          // 0..1023
    const int tid = threadIdx.x;
    for (int c = tid; c < GKW; c += 256) {
        unsigned short v = 0;
        if (row < NNODE && c < KDIM) v = f2bf(Wi[(size_t)row * (KDIM + 1) + 1 + c]);
        Ws[(size_t)row * GKW + c] = v;
    }
    if (tid == 0) bias[row] = (row < NNODE) ? Wi[(size_t)row * (KDIM + 1)] : 0.f;
}

// ===================== Pass A: 256x256, BK=32, 4-buffer counted-vmcnt MFMA =====================
#define BAR() { __builtin_amdgcn_sched_barrier(0); __builtin_amdgcn_s_barrier(); __builtin_amdgcn_sched_barrier(0); }

// stage tile kt into buffer (kt&3): 2 A-loads + 2 B-loads per thread (16B each)
#define STAGE(ktn)                                                                    \
    {                                                                                 \
        const int kt_ = (ktn);                                                        \
        const int kk_ = kt_ * 32;                                                     \
        unsigned short* ab_ = lds + (kt_ & 3) * 16384;                                \
        unsigned short* bb_ = ab_ + 8192;                                             \
        _Pragma("unroll")                                                             \
        for (int j = 0; j < 2; ++j)                                                   \
            __builtin_amdgcn_global_load_lds(                                         \
                (const __attribute__((address_space(1))) void*)(pA[j] + kk_),         \
                (__attribute__((address_space(3))) void*)(ab_ + (j * 512 + wave * 64) * 8), \
                16, 0, 0);                                                            \
        _Pragma("unroll")                                                             \
        for (int j = 0; j < 2; ++j)                                                   \
            __builtin_amdgcn_global_load_lds(                                         \
                (const __attribute__((address_space(1))) void*)(pB[j] + kk_),         \
                (__attribute__((address_space(3))) void*)(bb_ + (j * 512 + wave * 64) * 8), \
                16, 0, 0);                                                            \
    }

// fragment reads: row stride 32 shorts (64B); slot swizzle q4 ^ ((row>>1)&3)
#define LDA4(dst, mb, ab_)                                                            \
    _Pragma("unroll")                                                                 \
    for (int mi = 0; mi < 4; ++mi) {                                                  \
        const int row_ = wr * 128 + ((mb) + mi) * 16 + fr;                            \
        dst[mi] = *reinterpret_cast<const short8*>(                                   \
            (ab_) + row_ * 32 + ((q4 ^ ((row_ >> 1) & 3)) * 8));                      \
    }

#define LDB4(dst, bb_)                                                                \
    _Pragma("unroll")                                                                 \
    for (int n = 0; n < 4; ++n) {                                                     \
        const int row_ = wc * 64 + n * 16 + fr;                                       \
        dst[n] = *reinterpret_cast<const short8*>(                                    \
            (bb_) + row_ * 32 + ((q4 ^ ((row_ >> 1) & 3)) * 8));                      \
    }

#define MFMA16(mb, av, bv)                                                            \
    _Pragma("unroll")                                                                 \
    for (int mi = 0; mi < 4; ++mi)                                                    \
        _Pragma("unroll")                                                             \
        for (int n = 0; n < 4; ++n)                                                   \
            acc[(mb) + mi][n] = __builtin_amdgcn_mfma_f32_16x16x32_bf16(              \
                av[mi], bv[n], acc[(mb) + mi][n], 0, 0, 0);

__global__ __launch_bounds__(512, 2)
void sdt_gemm8(const unsigned short* __restrict__ Xs, const unsigned short* __restrict__ Ws,
               const float* __restrict__ bias, unsigned short* __restrict__ P)
{
    __shared__ __align__(16) unsigned short lds[65536];   // 128 KB = 4 buf x (A 16KB + B 16KB)

    const int tid  = threadIdx.x;
    const int wave = tid >> 6, lane = tid & 63;
    const int wr = wave >> 2, wc = wave & 3;              // 2x4 wave grid -> 128x64 per wave
    // XCD-aware swizzle: 512 blocks, 64 contiguous per XCD
    const int b  = blockIdx.x;
    const int wg = (b & 7) * 64 + (b >> 3);
    const int col0 = (wg & 3) * 256;
    const int row0 = (wg >> 2) * 256;

    const int fr = lane & 15;
    const int q4 = lane >> 4;

    f32x4 acc[8][4];
#pragma unroll
    for (int i = 0; i < 8; ++i)
#pragma unroll
        for (int j = 0; j < 4; ++j) acc[i][j] = (f32x4)0.f;

    // staging sources: chunk c = j*512 + tid -> (r = c>>2, slot = c&3,
    // logical kc = slot ^ ((r>>1)&3)); global addr pre-inverse-swizzled.
    const unsigned short* pA[2];
    const unsigned short* pB[2];
#pragma unroll
    for (int j = 0; j < 2; ++j) {
        const int c = j * 512 + tid;
        const int r = c >> 2;
        const int kc = (c & 3) ^ ((r >> 1) & 3);
        pA[j] = Xs + (size_t)(row0 + r) * GKS + kc * 8;
        pB[j] = Ws + (size_t)(col0 + r) * GKW + kc * 8;
    }

    STAGE(0);
    STAGE(1);
    asm volatile("s_waitcnt vmcnt(4)" ::: "memory");   // tile 0 staged; tile 1 in flight
    BAR();

#pragma unroll 1
    for (int kt = 0; kt < NT; ++kt) {
        const unsigned short* ab = lds + (kt & 3) * 16384;
        const unsigned short* bb = ab + 8192;
        short8 a[4], bfr[4];

        // ---- phase 0: m0-3 ----
        LDA4(a, 0, ab);
        LDB4(bfr, bb);
        if (kt + 2 < NT) STAGE(kt + 2);
        BAR();
        __builtin_amdgcn_s_setprio(1);
        MFMA16(0, a, bfr);
        __builtin_amdgcn_s_setprio(0);
        BAR();
        // ---- phase 1: m4-7 ----
        LDA4(a, 4, ab);
        // steady state: outstanding = S(kt+1) + S(kt+2) = 8 -> vmcnt(4) drains S(kt+1).
        // tail (kt >= NT-2): no S(kt+2) issued -> vmcnt(4) would be a no-op on
        // S(kt+1); use vmcnt(0) so the last tile's staging is fenced, not timed.
        if (kt < NT - 2) { asm volatile("s_waitcnt vmcnt(4)" ::: "memory"); }
        else             { asm volatile("s_waitcnt vmcnt(0)" ::: "memory"); }
        BAR();
        __builtin_amdgcn_s_setprio(1);
        MFMA16(4, a, bfr);
        __builtin_amdgcn_s_setprio(0);
        BAR();
    }

    // ---- epilogue: bias + sigmoid, per-wave LDS transpose, coalesced stores ----
    __syncthreads();
    unsigned short* tr = lds + wave * 8192;   // 16 KB per wave (128 rows x 64 cols bf16)
    float bv[4];
#pragma unroll
    for (int n = 0; n < 4; ++n) bv[n] = bias[col0 + wc * 64 + n * 16 + fr];

#pragma unroll
    for (int m = 0; m < 8; ++m)
#pragma unroll
        for (int reg = 0; reg < 4; ++reg) {
            const int rl = m * 16 + q4 * 4 + reg;
#pragma unroll
            for (int n = 0; n < 4; ++n) {
                const float z = acc[m][n][reg] + bv[n];
                const float p = 1.f / (1.f + __expf(-z));
                tr[rl * 64 + n * 16 + fr] = f2bf(p);
            }
        }
    // wave-private readback (no barrier needed)
#pragma unroll
    for (int it = 0; it < 16; ++it) {
        const int r  = it * 8 + (lane >> 3);
        const int c8 = (lane & 7) * 8;
        const uint4 v = *reinterpret_cast<const uint4*>(tr + r * 64 + c8);
        *reinterpret_cast<uint4*>(
            &P[(size_t)(row0 + wr * 128 + r) * NP + col0 + wc * 64 + c8]) = v;
    }
}

// ===================== Pass B: tree sweep + leaf GEMV + leaf sums =====================
// round-3 proven version (float LDS staging, 69 KB -> 2 blocks/CU)
__global__ __launch_bounds__(256)
void sdt_tree(const unsigned short* __restrict__ P, const float* __restrict__ Wl,
              float* __restrict__ Y, float* __restrict__ leafsum)
{
    __shared__ float wl[OUTD * NLEAF];   // 40 KB
    __shared__ float buf[4][NP];         // 16 KB (p row / leaf-sum scratch)
    __shared__ float red[4][832];        // 13 KB (y reduction, stride 13)
    const int tid = threadIdx.x;
    const int wave = tid >> 6, lane = tid & 63;

    for (int idx = tid; idx < (OUTD * NLEAF) / 4; idx += 256)
        reinterpret_cast<float4*>(wl)[idx] = reinterpret_cast<const float4*>(Wl)[idx];
    __syncthreads();

    float lsum[16];
#pragma unroll
    for (int i = 0; i < 16; ++i) lsum[i] = 0.f;

    float* pl = buf[wave];
    float* rd = red[wave];
    const int rowbase = blockIdx.x * 32 + wave * 8;
    const int o_r   = lane % 10;            // reduction role (lanes < 40)
    const int seg16 = (lane / 10) * 16;

    for (int r = 0; r < 8; ++r) {
        const int row = rowbase + r;
        const uint4* prow = reinterpret_cast<const uint4*>(P + (size_t)row * NP);
#pragma unroll
        for (int c = 0; c < 2; ++c) {
            const uint4 v = prow[lane + 64 * c];
            const int base = (lane + 64 * c) * 8;
            pl[base + 0] = bf2f((unsigned short)(v.x & 0xffffu));
            pl[base + 1] = bf2f((unsigned short)(v.x >> 16));
            pl[base + 2] = bf2f((unsigned short)(v.y & 0xffffu));
            pl[base + 3] = bf2f((unsigned short)(v.y >> 16));
            pl[base + 4] = bf2f((unsigned short)(v.z & 0xffffu));
            pl[base + 5] = bf2f((unsigned short)(v.z >> 16));
            pl[base + 6] = bf2f((unsigned short)(v.w & 0xffffu));
            pl[base + 7] = bf2f((unsigned short)(v.w >> 16));
        }

        // tree walk: root -> depth-6 node (63+lane)
        float mu = 1.f; int node = 0;
#pragma unroll
        for (int d = 0; d < 6; ++d) {
            const int bit = (lane >> (5 - d)) & 1;
            const float pv = pl[node];
            mu *= bit ? (1.f - pv) : pv;
            node = 2 * node + 1 + bit;
        }
        float m1[2], m2[4], m3[8], m4[16];
        {
            const float pv = pl[63 + lane];
            m1[0] = mu * pv; m1[1] = mu * (1.f - pv);
        }
#pragma unroll
        for (int i = 0; i < 2; ++i) {
            const float pv = pl[127 + 2 * lane + i];
            m2[2 * i] = m1[i] * pv; m2[2 * i + 1] = m1[i] * (1.f - pv);
        }
#pragma unroll
        for (int i = 0; i < 4; ++i) {
            const float pv = pl[255 + 4 * lane + i];
            m3[2 * i] = m2[i] * pv; m3[2 * i + 1] = m2[i] * (1.f - pv);
        }
#pragma unroll
        for (int i = 0; i < 8; ++i) {
            const float pv = pl[511 + 8 * lane + i];
            m4[2 * i] = m3[i] * pv; m4[2 * i + 1] = m3[i] * (1.f - pv);
        }
#pragma unroll
        for (int i = 0; i < 16; ++i) lsum[i] += m4[i];

        // y partials: lane owns leaves lane*16..+15, float4 wl reads
#pragma unroll
        for (int o = 0; o < OUTD; ++o) {
            float s = 0.f;
#pragma unroll
            for (int i4 = 0; i4 < 4; ++i4) {
                const float4 w4 = *reinterpret_cast<const float4*>(&wl[o * NLEAF + lane * 16 + i4 * 4]);
                s = fmaf(m4[4 * i4 + 0], w4.x, s);
                s = fmaf(m4[4 * i4 + 1], w4.y, s);
                s = fmaf(m4[4 * i4 + 2], w4.z, s);
                s = fmaf(m4[4 * i4 + 3], w4.w, s);
            }
            rd[lane * 13 + o] = s;
        }
        // reduce 64 partials per output via LDS transpose + 2 shuffles
        float s = 0.f;
        if (lane < 40) {
#pragma unroll
            for (int m = 0; m < 16; ++m) s += rd[(seg16 + m) * 13 + o_r];
        }
        s += __shfl_down(s, 20, 64);
        s += __shfl_down(s, 10, 64);
        if (lane < 10) Y[(size_t)row * OUTD + lane] = s;
    }

    __syncthreads();
#pragma unroll
    for (int i = 0; i < 16; ++i) {
        const int ii = (i + lane) & 15;
        buf[wave][lane * 16 + ii] = lsum[ii];
    }
    __syncthreads();
    for (int idx = tid; idx < NLEAF; idx += 256) {
        const float s = buf[0][idx] + buf[1][idx] + buf[2][idx] + buf[3][idx];
        atomicAdd(&leafsum[idx], s);
    }
}

// ============================ Pass C: penalty ============================
__global__ __launch_bounds__(1024)
void sdt_penalty(const float* __restrict__ leafsum, float* __restrict__ pen_out)
{
    __shared__ float t[NLEAF];
    __shared__ float red1[1024];
    const int tid = threadIdx.x;
    t[tid] = leafsum[tid];
    __syncthreads();
    float pen = 0.f;
    for (int d = NDEPTH; d >= 1; --d) {
        const int n = 1 << d;
        if (tid < n) {
            const float num = t[tid];
            const float par = t[tid & ~1] + t[tid | 1];
            const float a = num / par;
            const float coeff = LAMDA * exp2f((float)(1 - d));
            pen -= 0.5f * coeff * (logf(a) + logf(1.f - a));
        }
        float s = 0.f;
        if (tid < (n >> 1)) s = t[2 * tid] + t[2 * tid + 1];
        __syncthreads();
        if (tid < (n >> 1)) t[tid] = s;
        __syncthreads();
    }
    red1[tid] = pen;
    __syncthreads();
    for (int off = 512; off >= 1; off >>= 1) {
        if (tid < off) red1[tid] += red1[tid + off];
        __syncthreads();
    }
    if (tid == 0) pen_out[0] = red1[0];
}

// ================================ launch ================================
extern "C" void kernel_launch(void* const* d_in, const int* in_sizes, int n_in,
                              void* d_out, int out_size, void* d_ws, size_t ws_size,
                              hipStream_t stream)
{
    const float* X  = (const float*)d_in[0];
    const float* Wi = (const float*)d_in[1];
    const float* Wl = (const float*)d_in[2];
    float* Y   = (float*)d_out;
    float* pen = Y + (size_t)BROWS * OUTD;

    char* ws = (char*)d_ws;
    const size_t P_BYTES  = (size_t)BROWS * NP * 2;            // 67,108,864
    const size_t XS_BYTES = (size_t)BROWS * GKS * 2;           // 52,428,800
    const size_t WS_BYTES = (size_t)NP * GKW * 2;              // 1,638,400

    unsigned short* P   = (unsigned short*)ws;
    unsigned short* Xs  = (unsigned short*)(ws + P_BYTES);
    unsigned short* Wsp = (unsigned short*)(ws + P_BYTES + XS_BYTES);
    float* bias    = (float*)(ws + P_BYTES + XS_BYTES + WS_BYTES);
    float* leafsum = (float*)(ws + P_BYTES + XS_BYTES + WS_BYTES + 4096);

    hipMemsetAsync(leafsum, 0, NLEAF * sizeof(float), stream);
    sdt_xsplit<<<BROWS * 100 / 256, 256, 0, stream>>>(X, Xs);
    sdt_wsplit<<<1024, 256, 0, stream>>>(Wi, Wsp, bias);
    sdt_gemm8<<<512, 512, 0, stream>>>(Xs, Wsp, bias, P);
    sdt_tree<<<BROWS / 32, 256, 0, stream>>>(P, Wl, Y, leafsum);
    sdt_penalty<<<1, 1024, 0, stream>>>(leafsum, pen);
}